// Round 1
// baseline (690.525 us; speedup 1.0000x reference)
//
#include <hip/hip_runtime.h>
#include <hip/hip_bf16.h>

// Problem constants (from reference): B=16, L=4096, D=512, H=512
#define BB 16
#define LL 4096
#define DD 512
#define HH 512
#define MM (BB * LL)   // 65536 tokens
#define NTILES_H 8     // 512 / 64

// ---------------------------------------------------------------------------
// Kernel 1: fused MLP GEMM.
//   y[m, h] = hidden[m, :] @ w1[:, h]            (K = D = 512)
//   part[ht, m] = sum_{h in htile} relu(y + b1[h]) * w2[h]
// Tile: BM=64, BN=64, BK=32; 256 threads; each thread 4x4 outputs.
// Deterministic reduction (no atomics): 8 h-tile partials per token,
// summed sequentially in the scan kernel.
// ---------------------------------------------------------------------------
#define BM 64
#define BN 64
#define BK 32

__global__ __launch_bounds__(256) void mlp_gemm_kernel(
    const float* __restrict__ A,    // hidden (M, 512)
    const float* __restrict__ W1,   // (512, 512) row-major (D, H)
    const float* __restrict__ B1,   // (512,)
    const float* __restrict__ W2,   // (512,)
    float* __restrict__ part)       // (8, M)
{
    __shared__ __align__(16) float As[BK][BM];   // k-major (transposed stage)
    __shared__ __align__(16) float Bs[BK][BN];
    __shared__ float red[64][17];

    const int ht = blockIdx.x;        // 0..7   (fast dim -> blocks sharing mtile adjacent)
    const int mt = blockIdx.y;        // 0..1023
    const int t  = threadIdx.x;
    const int tx = t & 15;
    const int ty = t >> 4;
    const int row0 = mt * BM;
    const int n0   = ht * BN;

    float acc[4][4];
#pragma unroll
    for (int i = 0; i < 4; ++i)
#pragma unroll
        for (int j = 0; j < 4; ++j) acc[i][j] = 0.0f;

    for (int k0 = 0; k0 < DD; k0 += BK) {
        // Stage A tile (64 rows x 32 k), store transposed As[k][m]
#pragma unroll
        for (int i = 0; i < 2; ++i) {
            const int idx = t + i * 256;          // 0..511 float4 slots
            const int m   = idx >> 3;             // 0..63
            const int kq  = idx & 7;              // 0..7  (k0 + kq*4)
            const float4 a = *reinterpret_cast<const float4*>(
                &A[(size_t)(row0 + m) * DD + k0 + kq * 4]);
            As[kq * 4 + 0][m] = a.x;
            As[kq * 4 + 1][m] = a.y;
            As[kq * 4 + 2][m] = a.z;
            As[kq * 4 + 3][m] = a.w;
        }
        // Stage B tile (32 k x 64 h) natural layout
#pragma unroll
        for (int i = 0; i < 2; ++i) {
            const int idx = t + i * 256;
            const int kk  = idx >> 4;             // 0..31
            const int nq  = idx & 15;             // 0..15
            const float4 bv = *reinterpret_cast<const float4*>(
                &W1[(size_t)(k0 + kk) * HH + n0 + nq * 4]);
            *reinterpret_cast<float4*>(&Bs[kk][nq * 4]) = bv;
        }
        __syncthreads();

#pragma unroll
        for (int k = 0; k < BK; ++k) {
            const float4 av = *reinterpret_cast<const float4*>(&As[k][ty * 4]);
            const float4 bv = *reinterpret_cast<const float4*>(&Bs[k][tx * 4]);
            const float a[4]  = {av.x, av.y, av.z, av.w};
            const float bb[4] = {bv.x, bv.y, bv.z, bv.w};
#pragma unroll
            for (int i = 0; i < 4; ++i)
#pragma unroll
                for (int j = 0; j < 4; ++j)
                    acc[i][j] = fmaf(a[i], bb[j], acc[i][j]);
        }
        __syncthreads();
    }

    // Epilogue: relu(y + b1) * w2, reduce over the 64 h of this tile.
    const float4 b1v = *reinterpret_cast<const float4*>(&B1[n0 + tx * 4]);
    const float4 w2v = *reinterpret_cast<const float4*>(&W2[n0 + tx * 4]);
    const float b1a[4] = {b1v.x, b1v.y, b1v.z, b1v.w};
    const float w2a[4] = {w2v.x, w2v.y, w2v.z, w2v.w};
#pragma unroll
    for (int i = 0; i < 4; ++i) {
        float p = 0.0f;
#pragma unroll
        for (int j = 0; j < 4; ++j) {
            float y = acc[i][j] + b1a[j];
            y = (y > 0.0f) ? y : 0.0f;
            p = fmaf(y, w2a[j], p);
        }
        red[ty * 4 + i][tx] = p;
    }
    __syncthreads();
    if (t < 64) {
        float s = 0.0f;
#pragma unroll
        for (int q = 0; q < 16; ++q) s += red[t][q];
        part[(size_t)ht * MM + row0 + t] = s;
    }
}

// ---------------------------------------------------------------------------
// Kernel 2: per-row boundary decision + prefix scan.
// One block per batch row b; 1024 threads x 4 elements.
// Produces: bpos (boundary token indices, compacted), nb[b], len[b],
// shortened_attention_mask output.
// ---------------------------------------------------------------------------
__global__ __launch_bounds__(1024) void boundary_scan_kernel(
    const float* __restrict__ part,   // (8, M)
    const float* __restrict__ mask,   // (B, L)
    const float* __restrict__ u,      // (B, L)
    const float* __restrict__ b2,     // (1,)
    int* __restrict__ bpos,           // (B, L)
    int* __restrict__ nb,             // (B,)
    int* __restrict__ lenb,           // (B,)
    float* __restrict__ smask_out)    // (B, L)
{
    __shared__ int sdata[1024];
    __shared__ int s_len;
    const int b   = blockIdx.x;
    const int tid = threadIdx.x;
    const int base = b * LL;
    const float b2v = b2[0];

    // ---- phase 1: sequence length = sum(mask) ----
    float mv[4];
    int lm = 0;
#pragma unroll
    for (int j = 0; j < 4; ++j) {
        const int l = tid * 4 + j;
        mv[j] = mask[base + l];
        lm += (mv[j] != 0.0f) ? 1 : 0;
    }
    sdata[tid] = lm;
    __syncthreads();
    for (int off = 512; off > 0; off >>= 1) {
        if (tid < off) sdata[tid] += sdata[tid + off];
        __syncthreads();
    }
    if (tid == 0) s_len = sdata[0];
    __syncthreads();
    const int len = s_len;
    __syncthreads();   // protect sdata before reuse

    // ---- phase 2: hard boundary flags (+ forced at len-1 if len < L) ----
    int h[4];
    int cnt = 0;
#pragma unroll
    for (int j = 0; j < 4; ++j) {
        const int l = tid * 4 + j;
        float logit = b2v;
#pragma unroll
        for (int p = 0; p < NTILES_H; ++p) logit += part[(size_t)p * MM + base + l];
        const float uu = u[base + l];
        const float x  = logit + logf(uu) - log1pf(-uu);
        int hh = (x > 0.0f && mv[j] != 0.0f) ? 1 : 0;
        if (len < LL && l == len - 1) hh = 1;   // forced boundary on last real token
        h[j] = hh;
        cnt += hh;
    }

    // ---- inclusive scan over per-thread counts (Hillis-Steele in LDS) ----
    sdata[tid] = cnt;
    __syncthreads();
    for (int off = 1; off < 1024; off <<= 1) {
        int v = (tid >= off) ? sdata[tid - off] : 0;
        __syncthreads();
        sdata[tid] += v;
        __syncthreads();
    }
    const int excl  = sdata[tid] - cnt;
    const int total = sdata[1023];

    int pos = excl;
#pragma unroll
    for (int j = 0; j < 4; ++j) {
        if (h[j]) {
            bpos[base + pos] = tid * 4 + j;
            ++pos;
        }
    }
    if (tid == 0) {
        nb[b]   = total;
        lenb[b] = len;
    }
#pragma unroll
    for (int j = 0; j < 4; ++j) {
        const int l = tid * 4 + j;
        smask_out[base + l] = (l < total) ? 1.0f : 0.0f;
    }
}

// ---------------------------------------------------------------------------
// Kernel 3: segment mean pooling. One block per (b, s); 128 threads x float4.
// Segments are contiguous token ranges: s spans (bpos[s-1], bpos[s]].
// Rows s >= nb[b] are zero (d_out is poisoned, must write everything).
// ---------------------------------------------------------------------------
__global__ __launch_bounds__(128) void pool_kernel(
    const float* __restrict__ hidden,   // (B, L, D)
    const int* __restrict__ bpos,       // (B, L)
    const int* __restrict__ nb,         // (B,)
    float* __restrict__ out)            // (B, L, D)
{
    const int blk = blockIdx.x;
    const int b   = blk >> 12;        // / 4096
    const int s   = blk & (LL - 1);
    const int tid = threadIdx.x;      // 0..127 -> float4 column
    const int base = b * LL;

    float ax = 0.0f, ay = 0.0f, az = 0.0f, aw = 0.0f;
    const int n = nb[b];
    if (s < n) {
        const int start = (s == 0) ? 0 : (bpos[base + s - 1] + 1);
        const int end   = bpos[base + s];
        const float inv = 1.0f / (float)(end - start + 1);
        for (int tkn = start; tkn <= end; ++tkn) {
            const float4 v = *reinterpret_cast<const float4*>(
                &hidden[((size_t)(base + tkn)) * DD + tid * 4]);
            ax += v.x; ay += v.y; az += v.z; aw += v.w;
        }
        ax *= inv; ay *= inv; az *= inv; aw *= inv;
    }
    float4 r; r.x = ax; r.y = ay; r.z = az; r.w = aw;
    *reinterpret_cast<float4*>(&out[((size_t)(base + s)) * DD + tid * 4]) = r;
}

// ---------------------------------------------------------------------------
// Kernel 4: scalars. k = sum(nb), n = sum(len), binomial loss in double.
// ---------------------------------------------------------------------------
__global__ void finalize_kernel(
    const int* __restrict__ nb,
    const int* __restrict__ lenb,
    float* __restrict__ out)   // out[0]=loss, out[1]=k, out[2]=n
{
    if (threadIdx.x == 0 && blockIdx.x == 0) {
        int k = 0, n = 0;
        for (int b = 0; b < BB; ++b) { k += nb[b]; n += lenb[b]; }
        const double dk = (double)k, dn = (double)n, p = 0.25;
        const double logc = lgamma(dn + 1.0) - lgamma(dk + 1.0) - lgamma(dn - dk + 1.0);
        const double loss = -(logc + dk * log(p) + (dn - dk) * log1p(-p)) / dn;
        out[0] = (float)loss;
        out[1] = (float)k;
        out[2] = (float)n;
    }
}

// ---------------------------------------------------------------------------
extern "C" void kernel_launch(void* const* d_in, const int* in_sizes, int n_in,
                              void* d_out, int out_size, void* d_ws, size_t ws_size,
                              hipStream_t stream) {
    const float* hidden = (const float*)d_in[0];
    const float* mask   = (const float*)d_in[1];
    const float* u      = (const float*)d_in[2];
    const float* w1     = (const float*)d_in[3];
    const float* b1     = (const float*)d_in[4];
    const float* w2     = (const float*)d_in[5];
    const float* b2     = (const float*)d_in[6];
    float* out = (float*)d_out;

    char* ws = (char*)d_ws;
    float* part = (float*)ws;                                   // 8 * 65536 floats
    int*   bpos = (int*)(ws + (size_t)NTILES_H * MM * 4);       // 65536 ints
    int*   nbuf = (int*)(ws + (size_t)NTILES_H * MM * 4 + (size_t)MM * 4);
    int*   lenb = nbuf + BB;

    const size_t P = (size_t)MM * DD;        // pooled element count
    float* smask = out + P + 3;              // shortened_attention_mask

    mlp_gemm_kernel<<<dim3(NTILES_H, MM / BM), 256, 0, stream>>>(hidden, w1, b1, w2, part);
    boundary_scan_kernel<<<BB, 1024, 0, stream>>>(part, mask, u, b2, bpos, nbuf, lenb, smask);
    pool_kernel<<<MM, 128, 0, stream>>>(hidden, bpos, nbuf, out);
    finalize_kernel<<<1, 64, 0, stream>>>(nbuf, lenb, out + P);
}

// Round 2
// 398.222 us; speedup vs baseline: 1.7340x; 1.7340x over previous
//
#include <hip/hip_runtime.h>
#include <hip/hip_bf16.h>
#include <stdint.h>

// Problem constants (from reference): B=16, L=4096, D=512, H=512
#define BB 16
#define LL 4096
#define DD 512
#define HH 512
#define MM (BB * LL)   // 65536 tokens
#define NTILES_H 8     // partial count for the scan kernel (both paths)

typedef _Float16 f16x8 __attribute__((ext_vector_type(8)));
typedef float f32x4 __attribute__((ext_vector_type(4)));

// ===========================================================================
// FAST PATH: split-f16 MFMA GEMM
//   hidden (M,512) fp32 -> A_hi + A_lo (f16), residual scaled by 2^12
//   w1 scaled by 2^6 -> B_hi + B_lo (f16), residual scaled by 2^12
//   y = (acc_hihi + 2^-12 * (acc_hilo + acc_lohi)) * 2^-6
// Layout: per (tile of 128 rows x 32 k): 4096 f16, stored so that each
// lane's 8-elem MFMA fragment is one contiguous 16B unit, XOR-swizzled
// (q ^= row&3 on 16B units) for conflict-free ds_read_b128.
// ===========================================================================

// ---- conversion: hidden -> Ah/Al in tiled+swizzled layout -----------------
__global__ __launch_bounds__(256) void conv_a_kernel(
    const float* __restrict__ A, _Float16* __restrict__ Ah, _Float16* __restrict__ Al)
{
    const int t    = blockIdx.x * 256 + threadIdx.x;   // 0 .. 4M-1
    const int tile = t >> 9;                           // mt*16 + kt
    const int u    = t & 511;                          // 16B unit within tile
    const int ml   = u >> 2;                           // row 0..127
    const int q    = u & 3;                            // swizzled 16B slot
    const int mt   = tile >> 4;
    const int kt   = tile & 15;
    const int g    = q ^ (ml & 3);                     // k-group 0..3

    const float* src = A + ((size_t)(mt * 128 + ml)) * DD + kt * 32;
    const float4 x = *reinterpret_cast<const float4*>(src + 4 * g);
    const float4 y = *reinterpret_cast<const float4*>(src + 16 + 4 * g);
    const float v[8] = {x.x, x.y, x.z, x.w, y.x, y.y, y.z, y.w};

    f16x8 h, l;
#pragma unroll
    for (int e = 0; e < 8; ++e) {
        const _Float16 hh = (_Float16)v[e];
        const float r = v[e] - (float)hh;
        h[e] = hh;
        l[e] = (_Float16)(r * 4096.0f);
    }
    *reinterpret_cast<f16x8*>(Ah + (size_t)tile * 4096 + u * 8) = h;
    *reinterpret_cast<f16x8*>(Al + (size_t)tile * 4096 + u * 8) = l;
}

// ---- conversion: w1 (D,H) -> Bh/Bl, n-major tiles, scaled by 64 -----------
__global__ __launch_bounds__(256) void conv_b_kernel(
    const float* __restrict__ W1, _Float16* __restrict__ Bh, _Float16* __restrict__ Bl)
{
    const int t    = blockIdx.x * 256 + threadIdx.x;   // 0 .. 32767
    const int tile = t >> 9;                           // ht*16 + kt
    const int u    = t & 511;
    const int nl   = u >> 2;
    const int q    = u & 3;
    const int ht   = tile >> 4;
    const int kt   = tile & 15;
    const int g    = q ^ (nl & 3);

    const int n = ht * 128 + nl;
    const int kbase = kt * 32;
    f16x8 h, l;
#pragma unroll
    for (int e = 0; e < 8; ++e) {
        const int k = kbase + ((e < 4) ? (4 * g + e) : (16 + 4 * g + (e - 4)));
        const float v = W1[(size_t)k * HH + n] * 64.0f;
        const _Float16 hh = (_Float16)v;
        const float r = v - (float)hh;
        h[e] = hh;
        l[e] = (_Float16)(r * 4096.0f);
    }
    *reinterpret_cast<f16x8*>(Bh + (size_t)tile * 4096 + u * 8) = h;
    *reinterpret_cast<f16x8*>(Bl + (size_t)tile * 4096 + u * 8) = l;
}

__device__ __forceinline__ void gload16(const void* g, void* l)
{
    __builtin_amdgcn_global_load_lds(
        (const __attribute__((address_space(1))) unsigned int*)g,
        (__attribute__((address_space(3))) unsigned int*)l, 16, 0, 0);
}

// ---- MFMA GEMM + fused relu/w2 epilogue -----------------------------------
__global__ __launch_bounds__(256, 2) void gemm_mfma_kernel(
    const _Float16* __restrict__ Ah, const _Float16* __restrict__ Al,
    const _Float16* __restrict__ Bh, const _Float16* __restrict__ Bl,
    const float* __restrict__ B1,    const float* __restrict__ W2,
    float* __restrict__ part)        // (8, M): p = ht*2 + wc
{
    __shared__ __align__(16) char lds[2][4][8192];   // [buf][Ah,Al,Bh,Bl][bytes]

    // XCD-bijective decode: d = x + 8*ht + 32*mt_local ; mt = x*64 + mt_local
    const int d  = blockIdx.x;
    const int x  = d & 7;
    const int ht = (d >> 3) & 3;
    const int mt = x * 64 + (d >> 5);

    const int tid  = threadIdx.x;
    const int lane = tid & 63;
    const int w    = tid >> 6;       // wave 0..3
    const int wr   = w >> 1;         // m half
    const int wc   = w & 1;          // n half
    const int c    = lane & 15;
    const int g    = lane >> 4;

    // ds_read byte offsets (within one 8KB region)
    int aoff[4], boff[4];
#pragma unroll
    for (int f = 0; f < 4; ++f) {
        const int m_local = wr * 64 + f * 16 + c;
        aoff[f] = m_local * 64 + ((g ^ (c & 3)) << 4);
        const int n_local = wc * 64 + f * 16 + c;
        boff[f] = n_local * 64 + ((g ^ (c & 3)) << 4);
    }

    f32x4 accM[4][4] = {};
    f32x4 accL[4][4] = {};

    auto stage = [&](int kt, int b) {
        const _Float16* s0 = Ah + ((size_t)(mt * 16 + kt)) * 4096;
        const _Float16* s1 = Al + ((size_t)(mt * 16 + kt)) * 4096;
        const _Float16* s2 = Bh + ((size_t)(ht * 16 + kt)) * 4096;
        const _Float16* s3 = Bl + ((size_t)(ht * 16 + kt)) * 4096;
        char* l = &lds[b][0][0];
#pragma unroll
        for (int i = 0; i < 2; ++i) {
            const int e = (tid + i * 256) * 8;      // elem offset
            const int o = (tid + i * 256) * 16;     // byte offset
            gload16(s0 + e, l + 0 * 8192 + o);
            gload16(s1 + e, l + 1 * 8192 + o);
            gload16(s2 + e, l + 2 * 8192 + o);
            gload16(s3 + e, l + 3 * 8192 + o);
        }
    };

    stage(0, 0);
    int buf = 0;
    for (int kt = 0; kt < 16; ++kt) {
        __syncthreads();                       // staged buf ready; prev reads done
        if (kt + 1 < 16) stage(kt + 1, buf ^ 1);
        const char* base = &lds[buf][0][0];
        f16x8 ah[4], al[4];
#pragma unroll
        for (int mf = 0; mf < 4; ++mf) {
            ah[mf] = *reinterpret_cast<const f16x8*>(base + 0 * 8192 + aoff[mf]);
            al[mf] = *reinterpret_cast<const f16x8*>(base + 1 * 8192 + aoff[mf]);
        }
#pragma unroll
        for (int nf = 0; nf < 4; ++nf) {
            const f16x8 bh = *reinterpret_cast<const f16x8*>(base + 2 * 8192 + boff[nf]);
            const f16x8 bl = *reinterpret_cast<const f16x8*>(base + 3 * 8192 + boff[nf]);
#pragma unroll
            for (int mf = 0; mf < 4; ++mf) {
                accM[mf][nf] = __builtin_amdgcn_mfma_f32_16x16x32_f16(ah[mf], bh, accM[mf][nf], 0, 0, 0);
                accL[mf][nf] = __builtin_amdgcn_mfma_f32_16x16x32_f16(ah[mf], bl, accL[mf][nf], 0, 0, 0);
                accL[mf][nf] = __builtin_amdgcn_mfma_f32_16x16x32_f16(al[mf], bh, accL[mf][nf], 0, 0, 0);
            }
        }
        buf ^= 1;
    }

    // ---- epilogue: y = (accM + accL/4096)/64 + b1 ; relu ; dot w2 ---------
    float w2v[4], b1v[4];
#pragma unroll
    for (int nf = 0; nf < 4; ++nf) {
        const int n = ht * 128 + wc * 64 + nf * 16 + c;
        w2v[nf] = W2[n];
        b1v[nf] = B1[n];
    }
    float red[4][4];   // [mf][reg]
#pragma unroll
    for (int mf = 0; mf < 4; ++mf)
#pragma unroll
        for (int r = 0; r < 4; ++r) {
            float s = 0.0f;
#pragma unroll
            for (int nf = 0; nf < 4; ++nf) {
                float y = (accM[mf][nf][r] + accL[mf][nf][r] * (1.0f / 4096.0f)) * (1.0f / 64.0f) + b1v[nf];
                y = (y > 0.0f) ? y : 0.0f;
                s = fmaf(y, w2v[nf], s);
            }
            red[mf][r] = s;
        }
#pragma unroll
    for (int step = 1; step < 16; step <<= 1)
#pragma unroll
        for (int mf = 0; mf < 4; ++mf)
#pragma unroll
            for (int r = 0; r < 4; ++r)
                red[mf][r] += __shfl_xor(red[mf][r], step);
    if (c == 0) {
        const int p = ht * 2 + wc;
#pragma unroll
        for (int mf = 0; mf < 4; ++mf)
#pragma unroll
            for (int r = 0; r < 4; ++r) {
                const int m = mt * 128 + wr * 64 + mf * 16 + g * 4 + r;
                part[(size_t)p * MM + m] = red[mf][r];
            }
    }
}

// ===========================================================================
// FALLBACK PATH (proven R1 fp32 kernel) — used if workspace too small
// ===========================================================================
#define BM 64
#define BN 64
#define BK 32

__global__ __launch_bounds__(256) void mlp_gemm_kernel(
    const float* __restrict__ A, const float* __restrict__ W1,
    const float* __restrict__ B1, const float* __restrict__ W2,
    float* __restrict__ part)
{
    __shared__ __align__(16) float As[BK][BM];
    __shared__ __align__(16) float Bs[BK][BN];
    __shared__ float red[64][17];

    const int ht = blockIdx.x;
    const int mt = blockIdx.y;
    const int t  = threadIdx.x;
    const int tx = t & 15;
    const int ty = t >> 4;
    const int row0 = mt * BM;
    const int n0   = ht * BN;

    float acc[4][4];
#pragma unroll
    for (int i = 0; i < 4; ++i)
#pragma unroll
        for (int j = 0; j < 4; ++j) acc[i][j] = 0.0f;

    for (int k0 = 0; k0 < DD; k0 += BK) {
#pragma unroll
        for (int i = 0; i < 2; ++i) {
            const int idx = t + i * 256;
            const int m   = idx >> 3;
            const int kq  = idx & 7;
            const float4 a = *reinterpret_cast<const float4*>(
                &A[(size_t)(row0 + m) * DD + k0 + kq * 4]);
            As[kq * 4 + 0][m] = a.x;
            As[kq * 4 + 1][m] = a.y;
            As[kq * 4 + 2][m] = a.z;
            As[kq * 4 + 3][m] = a.w;
        }
#pragma unroll
        for (int i = 0; i < 2; ++i) {
            const int idx = t + i * 256;
            const int kk  = idx >> 4;
            const int nq  = idx & 15;
            const float4 bv = *reinterpret_cast<const float4*>(
                &W1[(size_t)(k0 + kk) * HH + n0 + nq * 4]);
            *reinterpret_cast<float4*>(&Bs[kk][nq * 4]) = bv;
        }
        __syncthreads();
#pragma unroll
        for (int k = 0; k < BK; ++k) {
            const float4 av = *reinterpret_cast<const float4*>(&As[k][ty * 4]);
            const float4 bv = *reinterpret_cast<const float4*>(&Bs[k][tx * 4]);
            const float a[4]  = {av.x, av.y, av.z, av.w};
            const float bb[4] = {bv.x, bv.y, bv.z, bv.w};
#pragma unroll
            for (int i = 0; i < 4; ++i)
#pragma unroll
                for (int j = 0; j < 4; ++j)
                    acc[i][j] = fmaf(a[i], bb[j], acc[i][j]);
        }
        __syncthreads();
    }

    const float4 b1v = *reinterpret_cast<const float4*>(&B1[n0 + tx * 4]);
    const float4 w2v = *reinterpret_cast<const float4*>(&W2[n0 + tx * 4]);
    const float b1a[4] = {b1v.x, b1v.y, b1v.z, b1v.w};
    const float w2a[4] = {w2v.x, w2v.y, w2v.z, w2v.w};
#pragma unroll
    for (int i = 0; i < 4; ++i) {
        float p = 0.0f;
#pragma unroll
        for (int j = 0; j < 4; ++j) {
            float y = acc[i][j] + b1a[j];
            y = (y > 0.0f) ? y : 0.0f;
            p = fmaf(y, w2a[j], p);
        }
        red[ty * 4 + i][tx] = p;
    }
    __syncthreads();
    if (t < 64) {
        float s = 0.0f;
#pragma unroll
        for (int q = 0; q < 16; ++q) s += red[t][q];
        part[(size_t)(t & 0) * 0 + (size_t)blockIdx.x * MM + row0 + t] = s;
    }
}

// ===========================================================================
// Kernel 2: per-row boundary decision + prefix scan (sums 8 partials)
// ===========================================================================
__global__ __launch_bounds__(1024) void boundary_scan_kernel(
    const float* __restrict__ part, const float* __restrict__ mask,
    const float* __restrict__ u,    const float* __restrict__ b2,
    int* __restrict__ bpos, int* __restrict__ nb, int* __restrict__ lenb,
    float* __restrict__ smask_out)
{
    __shared__ int sdata[1024];
    __shared__ int s_len;
    const int b   = blockIdx.x;
    const int tid = threadIdx.x;
    const int base = b * LL;
    const float b2v = b2[0];

    float mv[4];
    int lm = 0;
#pragma unroll
    for (int j = 0; j < 4; ++j) {
        const int l = tid * 4 + j;
        mv[j] = mask[base + l];
        lm += (mv[j] != 0.0f) ? 1 : 0;
    }
    sdata[tid] = lm;
    __syncthreads();
    for (int off = 512; off > 0; off >>= 1) {
        if (tid < off) sdata[tid] += sdata[tid + off];
        __syncthreads();
    }
    if (tid == 0) s_len = sdata[0];
    __syncthreads();
    const int len = s_len;
    __syncthreads();

    int h[4];
    int cnt = 0;
#pragma unroll
    for (int j = 0; j < 4; ++j) {
        const int l = tid * 4 + j;
        float logit = b2v;
#pragma unroll
        for (int p = 0; p < NTILES_H; ++p) logit += part[(size_t)p * MM + base + l];
        const float uu = u[base + l];
        const float xx = logit + logf(uu) - log1pf(-uu);
        int hh = (xx > 0.0f && mv[j] != 0.0f) ? 1 : 0;
        if (len < LL && l == len - 1) hh = 1;
        h[j] = hh;
        cnt += hh;
    }

    sdata[tid] = cnt;
    __syncthreads();
    for (int off = 1; off < 1024; off <<= 1) {
        int v = (tid >= off) ? sdata[tid - off] : 0;
        __syncthreads();
        sdata[tid] += v;
        __syncthreads();
    }
    const int excl  = sdata[tid] - cnt;
    const int total = sdata[1023];

    int pos = excl;
#pragma unroll
    for (int j = 0; j < 4; ++j) {
        if (h[j]) {
            bpos[base + pos] = tid * 4 + j;
            ++pos;
        }
    }
    if (tid == 0) {
        nb[b]   = total;
        lenb[b] = len;
    }
#pragma unroll
    for (int j = 0; j < 4; ++j) {
        const int l = tid * 4 + j;
        smask_out[base + l] = (l < total) ? 1.0f : 0.0f;
    }
}

// ===========================================================================
// Kernel 3: segment mean pooling
// ===========================================================================
__global__ __launch_bounds__(128) void pool_kernel(
    const float* __restrict__ hidden, const int* __restrict__ bpos,
    const int* __restrict__ nb, float* __restrict__ out)
{
    const int blk = blockIdx.x;
    const int b   = blk >> 12;
    const int s   = blk & (LL - 1);
    const int tid = threadIdx.x;
    const int base = b * LL;

    float ax = 0.0f, ay = 0.0f, az = 0.0f, aw = 0.0f;
    const int n = nb[b];
    if (s < n) {
        const int start = (s == 0) ? 0 : (bpos[base + s - 1] + 1);
        const int end   = bpos[base + s];
        const float inv = 1.0f / (float)(end - start + 1);
        for (int tkn = start; tkn <= end; ++tkn) {
            const float4 v = *reinterpret_cast<const float4*>(
                &hidden[((size_t)(base + tkn)) * DD + tid * 4]);
            ax += v.x; ay += v.y; az += v.z; aw += v.w;
        }
        ax *= inv; ay *= inv; az *= inv; aw *= inv;
    }
    float4 r; r.x = ax; r.y = ay; r.z = az; r.w = aw;
    *reinterpret_cast<float4*>(&out[((size_t)(base + s)) * DD + tid * 4]) = r;
}

// ===========================================================================
// Kernel 4: scalars
// ===========================================================================
__global__ void finalize_kernel(
    const int* __restrict__ nb, const int* __restrict__ lenb,
    float* __restrict__ out)
{
    if (threadIdx.x == 0 && blockIdx.x == 0) {
        int k = 0, n = 0;
        for (int b = 0; b < BB; ++b) { k += nb[b]; n += lenb[b]; }
        const double dk = (double)k, dn = (double)n, p = 0.25;
        const double logc = lgamma(dn + 1.0) - lgamma(dk + 1.0) - lgamma(dn - dk + 1.0);
        const double loss = -(logc + dk * log(p) + (dn - dk) * log1p(-p)) / dn;
        out[0] = (float)loss;
        out[1] = (float)k;
        out[2] = (float)n;
    }
}

// ===========================================================================
extern "C" void kernel_launch(void* const* d_in, const int* in_sizes, int n_in,
                              void* d_out, int out_size, void* d_ws, size_t ws_size,
                              hipStream_t stream) {
    const float* hidden = (const float*)d_in[0];
    const float* mask   = (const float*)d_in[1];
    const float* u      = (const float*)d_in[2];
    const float* w1     = (const float*)d_in[3];
    const float* b1     = (const float*)d_in[4];
    const float* w2     = (const float*)d_in[5];
    const float* b2     = (const float*)d_in[6];
    float* out = (float*)d_out;

    const size_t AH_BYTES = (size_t)8192 * 4096 * 2;   // 64 MB
    const size_t BH_BYTES = (size_t)64 * 4096 * 2;     // 512 KB
    const size_t PART_BYTES = (size_t)NTILES_H * MM * 4;
    const size_t BPOS_BYTES = (size_t)MM * 4;
    const size_t need = AH_BYTES * 2 + BH_BYTES * 2 + PART_BYTES + BPOS_BYTES + 128;

    const size_t P = (size_t)MM * DD;
    float* smask = out + P + 3;

    char* ws = (char*)d_ws;
    float* part; int* bpos; int* nbuf; int* lenb;

    if (ws_size >= need) {
        _Float16* Ah = (_Float16*)ws;
        _Float16* Al = (_Float16*)(ws + AH_BYTES);
        _Float16* Bh = (_Float16*)(ws + AH_BYTES * 2);
        _Float16* Bl = (_Float16*)(ws + AH_BYTES * 2 + BH_BYTES);
        part = (float*)(ws + AH_BYTES * 2 + BH_BYTES * 2);
        bpos = (int*)(ws + AH_BYTES * 2 + BH_BYTES * 2 + PART_BYTES);
        nbuf = (int*)(ws + AH_BYTES * 2 + BH_BYTES * 2 + PART_BYTES + BPOS_BYTES);
        lenb = nbuf + BB;

        conv_a_kernel<<<16384, 256, 0, stream>>>(hidden, Ah, Al);
        conv_b_kernel<<<128, 256, 0, stream>>>(w1, Bh, Bl);
        gemm_mfma_kernel<<<2048, 256, 0, stream>>>(Ah, Al, Bh, Bl, b1, w2, part);
    } else {
        part = (float*)ws;
        bpos = (int*)(ws + PART_BYTES);
        nbuf = (int*)(ws + PART_BYTES + BPOS_BYTES);
        lenb = nbuf + BB;
        mlp_gemm_kernel<<<dim3(NTILES_H, MM / BM), 256, 0, stream>>>(hidden, w1, b1, w2, part);
    }

    boundary_scan_kernel<<<BB, 1024, 0, stream>>>(part, mask, u, b2, bpos, nbuf, lenb, smask);
    pool_kernel<<<MM, 128, 0, stream>>>(hidden, bpos, nbuf, out);
    finalize_kernel<<<1, 64, 0, stream>>>(nbuf, lenb, out + P);
}

// Round 3
// 397.844 us; speedup vs baseline: 1.7357x; 1.0009x over previous
//
#include <hip/hip_runtime.h>
#include <hip/hip_bf16.h>
#include <stdint.h>

// Problem constants (from reference): B=16, L=4096, D=512, H=512
#define BB 16
#define LL 4096
#define DD 512
#define HH 512
#define MM (BB * LL)   // 65536 tokens
#define NTILES_H 8     // partial count for the scan kernel (both paths)

typedef _Float16 f16x8 __attribute__((ext_vector_type(8)));
typedef float f32x4 __attribute__((ext_vector_type(4)));

// ===========================================================================
// FAST PATH: split-f16 MFMA GEMM
//   hidden (M,512) fp32 -> A_hi + A_lo (f16), residual scaled by 2^12
//   w1 scaled by 2^6 -> B_hi + B_lo (f16), residual scaled by 2^12
//   y = (acc_hihi + 2^-12 * (acc_hilo + acc_lohi)) * 2^-6
// Layout: per (tile of 128 rows x 32 k): 4096 f16; each lane's 8-elem MFMA
// fragment is one contiguous 16B unit. Swizzle on 16B units:
//   q = g ^ (row&3) ^ ((row>>2)&3)
// so that within any 16 consecutive rows each bank-quad is hit exactly
// twice (2-way = free) instead of 4-way.
// ===========================================================================

// ---- conversion: hidden -> Ah/Al in tiled+swizzled layout -----------------
__global__ __launch_bounds__(256) void conv_a_kernel(
    const float* __restrict__ A, _Float16* __restrict__ Ah, _Float16* __restrict__ Al)
{
    const int t    = blockIdx.x * 256 + threadIdx.x;   // 0 .. 4M-1
    const int tile = t >> 9;                           // mt*16 + kt
    const int u    = t & 511;                          // 16B unit within tile
    const int ml   = u >> 2;                           // row 0..127
    const int q    = u & 3;                            // swizzled 16B slot
    const int mt   = tile >> 4;
    const int kt   = tile & 15;
    const int g    = q ^ (ml & 3) ^ ((ml >> 2) & 3);   // k-group 0..3

    const float* src = A + ((size_t)(mt * 128 + ml)) * DD + kt * 32;
    const float4 x = *reinterpret_cast<const float4*>(src + 4 * g);
    const float4 y = *reinterpret_cast<const float4*>(src + 16 + 4 * g);
    const float v[8] = {x.x, x.y, x.z, x.w, y.x, y.y, y.z, y.w};

    f16x8 h, l;
#pragma unroll
    for (int e = 0; e < 8; ++e) {
        const _Float16 hh = (_Float16)v[e];
        const float r = v[e] - (float)hh;
        h[e] = hh;
        l[e] = (_Float16)(r * 4096.0f);
    }
    *reinterpret_cast<f16x8*>(Ah + (size_t)tile * 4096 + u * 8) = h;
    *reinterpret_cast<f16x8*>(Al + (size_t)tile * 4096 + u * 8) = l;
}

// ---- conversion: w1 (D,H) -> Bh/Bl, n-major tiles, scaled by 64 -----------
__global__ __launch_bounds__(256) void conv_b_kernel(
    const float* __restrict__ W1, _Float16* __restrict__ Bh, _Float16* __restrict__ Bl)
{
    const int t    = blockIdx.x * 256 + threadIdx.x;   // 0 .. 32767
    const int tile = t >> 9;                           // ht*16 + kt
    const int u    = t & 511;
    const int nl   = u >> 2;
    const int q    = u & 3;
    const int ht   = tile >> 4;
    const int kt   = tile & 15;
    const int g    = q ^ (nl & 3) ^ ((nl >> 2) & 3);

    const int n = ht * 128 + nl;
    const int kbase = kt * 32;
    f16x8 h, l;
#pragma unroll
    for (int e = 0; e < 8; ++e) {
        const int k = kbase + ((e < 4) ? (4 * g + e) : (16 + 4 * g + (e - 4)));
        const float v = W1[(size_t)k * HH + n] * 64.0f;
        const _Float16 hh = (_Float16)v;
        const float r = v - (float)hh;
        h[e] = hh;
        l[e] = (_Float16)(r * 4096.0f);
    }
    *reinterpret_cast<f16x8*>(Bh + (size_t)tile * 4096 + u * 8) = h;
    *reinterpret_cast<f16x8*>(Bl + (size_t)tile * 4096 + u * 8) = l;
}

__device__ __forceinline__ void gload16(const void* g, void* l)
{
    __builtin_amdgcn_global_load_lds(
        (const __attribute__((address_space(1))) unsigned int*)g,
        (__attribute__((address_space(3))) unsigned int*)l, 16, 0, 0);
}

// ---- MFMA GEMM + fused relu/w2 epilogue -----------------------------------
__global__ __launch_bounds__(256, 2) void gemm_mfma_kernel(
    const _Float16* __restrict__ Ah, const _Float16* __restrict__ Al,
    const _Float16* __restrict__ Bh, const _Float16* __restrict__ Bl,
    const float* __restrict__ B1,    const float* __restrict__ W2,
    float* __restrict__ part)        // (8, M): p = ht*2 + wc
{
    __shared__ __align__(16) char lds[2][4][8192];   // [buf][Ah,Al,Bh,Bl][bytes]

    // XCD-bijective decode: d = x + 8*ht + 32*mt_local ; mt = x*64 + mt_local
    const int d  = blockIdx.x;
    const int x  = d & 7;
    const int ht = (d >> 3) & 3;
    const int mt = x * 64 + (d >> 5);

    const int tid  = threadIdx.x;
    const int lane = tid & 63;
    const int w    = tid >> 6;       // wave 0..3
    const int wr   = w >> 1;         // m half
    const int wc   = w & 1;          // n half
    const int c    = lane & 15;
    const int g    = lane >> 4;

    // ds_read byte offsets (within one 8KB region), swizzle-matched to conv
    const int q = g ^ (c & 3) ^ ((c >> 2) & 3);
    int aoff[4], boff[4];
#pragma unroll
    for (int f = 0; f < 4; ++f) {
        const int m_local = wr * 64 + f * 16 + c;
        aoff[f] = m_local * 64 + (q << 4);
        const int n_local = wc * 64 + f * 16 + c;
        boff[f] = n_local * 64 + (q << 4);
    }

    f32x4 accM[4][4] = {};
    f32x4 accL[4][4] = {};

    auto stage = [&](int kt, int b) {
        const _Float16* s0 = Ah + ((size_t)(mt * 16 + kt)) * 4096;
        const _Float16* s1 = Al + ((size_t)(mt * 16 + kt)) * 4096;
        const _Float16* s2 = Bh + ((size_t)(ht * 16 + kt)) * 4096;
        const _Float16* s3 = Bl + ((size_t)(ht * 16 + kt)) * 4096;
        char* l = &lds[b][0][0];
#pragma unroll
        for (int i = 0; i < 2; ++i) {
            const int e = (tid + i * 256) * 8;      // elem offset
            const int o = (tid + i * 256) * 16;     // byte offset
            gload16(s0 + e, l + 0 * 8192 + o);
            gload16(s1 + e, l + 1 * 8192 + o);
            gload16(s2 + e, l + 2 * 8192 + o);
            gload16(s3 + e, l + 3 * 8192 + o);
        }
    };

    stage(0, 0);
    int buf = 0;
    for (int kt = 0; kt < 16; ++kt) {
        __syncthreads();                       // staged buf ready; prev reads done
        if (kt + 1 < 16) stage(kt + 1, buf ^ 1);
        const char* base = &lds[buf][0][0];
        f16x8 ah[4], al[4];
#pragma unroll
        for (int mf = 0; mf < 4; ++mf) {
            ah[mf] = *reinterpret_cast<const f16x8*>(base + 0 * 8192 + aoff[mf]);
            al[mf] = *reinterpret_cast<const f16x8*>(base + 1 * 8192 + aoff[mf]);
        }
#pragma unroll
        for (int nf = 0; nf < 4; ++nf) {
            const f16x8 bh = *reinterpret_cast<const f16x8*>(base + 2 * 8192 + boff[nf]);
            const f16x8 bl = *reinterpret_cast<const f16x8*>(base + 3 * 8192 + boff[nf]);
#pragma unroll
            for (int mf = 0; mf < 4; ++mf) {
                accM[mf][nf] = __builtin_amdgcn_mfma_f32_16x16x32_f16(ah[mf], bh, accM[mf][nf], 0, 0, 0);
                accL[mf][nf] = __builtin_amdgcn_mfma_f32_16x16x32_f16(ah[mf], bl, accL[mf][nf], 0, 0, 0);
                accL[mf][nf] = __builtin_amdgcn_mfma_f32_16x16x32_f16(al[mf], bh, accL[mf][nf], 0, 0, 0);
            }
        }
        buf ^= 1;
    }

    // ---- epilogue: y = (accM + accL/4096)/64 + b1 ; relu ; dot w2 ---------
    float w2v[4], b1v[4];
#pragma unroll
    for (int nf = 0; nf < 4; ++nf) {
        const int n = ht * 128 + wc * 64 + nf * 16 + c;
        w2v[nf] = W2[n];
        b1v[nf] = B1[n];
    }
    float red[4][4];   // [mf][reg]
#pragma unroll
    for (int mf = 0; mf < 4; ++mf)
#pragma unroll
        for (int r = 0; r < 4; ++r) {
            float s = 0.0f;
#pragma unroll
            for (int nf = 0; nf < 4; ++nf) {
                float y = (accM[mf][nf][r] + accL[mf][nf][r] * (1.0f / 4096.0f)) * (1.0f / 64.0f) + b1v[nf];
                y = (y > 0.0f) ? y : 0.0f;
                s = fmaf(y, w2v[nf], s);
            }
            red[mf][r] = s;
        }
#pragma unroll
    for (int step = 1; step < 16; step <<= 1)
#pragma unroll
        for (int mf = 0; mf < 4; ++mf)
#pragma unroll
            for (int r = 0; r < 4; ++r)
                red[mf][r] += __shfl_xor(red[mf][r], step);
    if (c == 0) {
        const int p = ht * 2 + wc;
#pragma unroll
        for (int mf = 0; mf < 4; ++mf)
#pragma unroll
            for (int r = 0; r < 4; ++r) {
                const int m = mt * 128 + wr * 64 + mf * 16 + g * 4 + r;
                part[(size_t)p * MM + m] = red[mf][r];
            }
    }
}

// ===========================================================================
// FALLBACK fp32 GEMM (used only if workspace too small)
// ===========================================================================
#define BM 64
#define BN 64
#define BK 32

__global__ __launch_bounds__(256) void mlp_gemm_kernel(
    const float* __restrict__ A, const float* __restrict__ W1,
    const float* __restrict__ B1, const float* __restrict__ W2,
    float* __restrict__ part)
{
    __shared__ __align__(16) float As[BK][BM];
    __shared__ __align__(16) float Bs[BK][BN];
    __shared__ float red[64][17];

    const int ht = blockIdx.x;
    const int mt = blockIdx.y;
    const int t  = threadIdx.x;
    const int tx = t & 15;
    const int ty = t >> 4;
    const int row0 = mt * BM;
    const int n0   = ht * BN;

    float acc[4][4];
#pragma unroll
    for (int i = 0; i < 4; ++i)
#pragma unroll
        for (int j = 0; j < 4; ++j) acc[i][j] = 0.0f;

    for (int k0 = 0; k0 < DD; k0 += BK) {
#pragma unroll
        for (int i = 0; i < 2; ++i) {
            const int idx = t + i * 256;
            const int m   = idx >> 3;
            const int kq  = idx & 7;
            const float4 a = *reinterpret_cast<const float4*>(
                &A[(size_t)(row0 + m) * DD + k0 + kq * 4]);
            As[kq * 4 + 0][m] = a.x;
            As[kq * 4 + 1][m] = a.y;
            As[kq * 4 + 2][m] = a.z;
            As[kq * 4 + 3][m] = a.w;
        }
#pragma unroll
        for (int i = 0; i < 2; ++i) {
            const int idx = t + i * 256;
            const int kk  = idx >> 4;
            const int nq  = idx & 15;
            const float4 bv = *reinterpret_cast<const float4*>(
                &W1[(size_t)(k0 + kk) * HH + n0 + nq * 4]);
            *reinterpret_cast<float4*>(&Bs[kk][nq * 4]) = bv;
        }
        __syncthreads();
#pragma unroll
        for (int k = 0; k < BK; ++k) {
            const float4 av = *reinterpret_cast<const float4*>(&As[k][ty * 4]);
            const float4 bv = *reinterpret_cast<const float4*>(&Bs[k][tx * 4]);
            const float a[4]  = {av.x, av.y, av.z, av.w};
            const float bb[4] = {bv.x, bv.y, bv.z, bv.w};
#pragma unroll
            for (int i = 0; i < 4; ++i)
#pragma unroll
                for (int j = 0; j < 4; ++j)
                    acc[i][j] = fmaf(a[i], bb[j], acc[i][j]);
        }
        __syncthreads();
    }

    const float4 b1v = *reinterpret_cast<const float4*>(&B1[n0 + tx * 4]);
    const float4 w2v = *reinterpret_cast<const float4*>(&W2[n0 + tx * 4]);
    const float b1a[4] = {b1v.x, b1v.y, b1v.z, b1v.w};
    const float w2a[4] = {w2v.x, w2v.y, w2v.z, w2v.w};
#pragma unroll
    for (int i = 0; i < 4; ++i) {
        float p = 0.0f;
#pragma unroll
        for (int j = 0; j < 4; ++j) {
            float y = acc[i][j] + b1a[j];
            y = (y > 0.0f) ? y : 0.0f;
            p = fmaf(y, w2a[j], p);
        }
        red[ty * 4 + i][tx] = p;
    }
    __syncthreads();
    if (t < 64) {
        float s = 0.0f;
#pragma unroll
        for (int q = 0; q < 16; ++q) s += red[t][q];
        part[(size_t)ht * MM + row0 + t] = s;
    }
}

// ===========================================================================
// Boundary pipeline (wide, replaces the 16-block scan)
// ===========================================================================

// ---- lengths: mask rows are monotone 1...10...0 -> binary search ----------
__global__ void len_kernel(const float* __restrict__ mask, int* __restrict__ lenb)
{
    const int b = threadIdx.x;
    if (b < BB) {
        const float* row = mask + b * LL;
        int lo = 0, hi = LL;          // smallest l with row[l]==0 (or L)
        while (lo < hi) {
            const int mid = (lo + hi) >> 1;
            if (row[mid] == 0.0f) hi = mid; else lo = mid + 1;
        }
        lenb[b] = lo;
    }
}

// ---- hard flags + per-chunk(256) counts -----------------------------------
__global__ __launch_bounds__(256) void flags_kernel(
    const float* __restrict__ part, const float* __restrict__ u,
    const float* __restrict__ b2,   const int* __restrict__ lenb,
    int* __restrict__ flags, int* __restrict__ chunkcnt)
{
    __shared__ int wsum[4];
    const int m   = blockIdx.x * 256 + threadIdx.x;
    const int b   = m >> 12;
    const int l   = m & (LL - 1);
    const int len = lenb[b];

    float logit = b2[0];
#pragma unroll
    for (int p = 0; p < NTILES_H; ++p) logit += part[(size_t)p * MM + m];
    const float uu = u[m];
    const float xx = logit + logf(uu) - log1pf(-uu);

    int hh = (xx > 0.0f && l < len) ? 1 : 0;
    if (len < LL && l == len - 1) hh = 1;
    flags[m] = hh;

    const unsigned long long bal = __ballot(hh);
    const int lane = threadIdx.x & 63;
    const int wid  = threadIdx.x >> 6;
    if (lane == 0) wsum[wid] = __popcll(bal);
    __syncthreads();
    if (threadIdx.x == 0)
        chunkcnt[blockIdx.x] = wsum[0] + wsum[1] + wsum[2] + wsum[3];
}

// ---- compaction: chunk offsets + in-wave ballot scan ----------------------
__global__ __launch_bounds__(256) void scan_kernel(
    const int* __restrict__ flags, const int* __restrict__ chunkcnt,
    int* __restrict__ bpos, int* __restrict__ nb, float* __restrict__ smask_out)
{
    __shared__ int s_chunk[16];
    __shared__ int wsum[4];
    const int bid   = blockIdx.x;
    const int b     = bid >> 4;
    const int chunk = bid & 15;
    const int tid   = threadIdx.x;
    const int m     = bid * 256 + tid;
    const int l     = m & (LL - 1);

    if (tid < 16) s_chunk[tid] = chunkcnt[b * 16 + tid];

    const int hh = flags[m];
    const unsigned long long bal = __ballot(hh);
    const int lane = tid & 63;
    const int wid  = tid >> 6;
    if (lane == 0) wsum[wid] = __popcll(bal);
    __syncthreads();

    int pre = 0, tot = 0;
#pragma unroll
    for (int i = 0; i < 16; ++i) {
        const int ci = s_chunk[i];
        pre += (i < chunk) ? ci : 0;
        tot += ci;
    }
    int woff = 0;
#pragma unroll
    for (int i = 0; i < 4; ++i) woff += (i < wid) ? wsum[i] : 0;

    if (hh) {
        const int excl = __popcll(bal & ((1ull << lane) - 1ull));
        bpos[b * LL + pre + woff + excl] = l;
    }
    smask_out[m] = (l < tot) ? 1.0f : 0.0f;
    if (chunk == 0 && tid == 0) nb[b] = tot;
}

// ===========================================================================
// Segment mean pooling
// ===========================================================================
__global__ __launch_bounds__(128) void pool_kernel(
    const float* __restrict__ hidden, const int* __restrict__ bpos,
    const int* __restrict__ nb, float* __restrict__ out)
{
    const int blk = blockIdx.x;
    const int b   = blk >> 12;
    const int s   = blk & (LL - 1);
    const int tid = threadIdx.x;
    const int base = b * LL;

    float ax = 0.0f, ay = 0.0f, az = 0.0f, aw = 0.0f;
    const int n = nb[b];
    if (s < n) {
        const int start = (s == 0) ? 0 : (bpos[base + s - 1] + 1);
        const int end   = bpos[base + s];
        const float inv = 1.0f / (float)(end - start + 1);
        for (int tkn = start; tkn <= end; ++tkn) {
            const float4 v = *reinterpret_cast<const float4*>(
                &hidden[((size_t)(base + tkn)) * DD + tid * 4]);
            ax += v.x; ay += v.y; az += v.z; aw += v.w;
        }
        ax *= inv; ay *= inv; az *= inv; aw *= inv;
    }
    float4 r; r.x = ax; r.y = ay; r.z = az; r.w = aw;
    *reinterpret_cast<float4*>(&out[((size_t)(base + s)) * DD + tid * 4]) = r;
}

// ===========================================================================
// Scalars
// ===========================================================================
__global__ void finalize_kernel(
    const int* __restrict__ nb, const int* __restrict__ lenb,
    float* __restrict__ out)
{
    if (threadIdx.x == 0 && blockIdx.x == 0) {
        int k = 0, n = 0;
        for (int b = 0; b < BB; ++b) { k += nb[b]; n += lenb[b]; }
        const double dk = (double)k, dn = (double)n, p = 0.25;
        const double logc = lgamma(dn + 1.0) - lgamma(dk + 1.0) - lgamma(dn - dk + 1.0);
        const double loss = -(logc + dk * log(p) + (dn - dk) * log1p(-p)) / dn;
        out[0] = (float)loss;
        out[1] = (float)k;
        out[2] = (float)n;
    }
}

// ===========================================================================
extern "C" void kernel_launch(void* const* d_in, const int* in_sizes, int n_in,
                              void* d_out, int out_size, void* d_ws, size_t ws_size,
                              hipStream_t stream) {
    const float* hidden = (const float*)d_in[0];
    const float* mask   = (const float*)d_in[1];
    const float* u      = (const float*)d_in[2];
    const float* w1     = (const float*)d_in[3];
    const float* b1     = (const float*)d_in[4];
    const float* w2     = (const float*)d_in[5];
    const float* b2     = (const float*)d_in[6];
    float* out = (float*)d_out;

    const size_t AH_BYTES   = (size_t)8192 * 4096 * 2;   // 64 MB
    const size_t BH_BYTES   = (size_t)64 * 4096 * 2;     // 512 KB
    const size_t PART_BYTES = (size_t)NTILES_H * MM * 4;
    const size_t BPOS_BYTES = (size_t)MM * 4;
    const size_t FLAG_BYTES = (size_t)MM * 4;
    const size_t need = AH_BYTES * 2 + BH_BYTES * 2 + PART_BYTES + BPOS_BYTES + FLAG_BYTES + 4096;

    const size_t P = (size_t)MM * DD;
    float* smask = out + P + 3;

    char* ws = (char*)d_ws;
    float* part; int* bpos; int* flags; int* chunkcnt; int* nbuf; int* lenb;
    bool fast = (ws_size >= need);

    char* tail;
    if (fast) tail = ws + AH_BYTES * 2 + BH_BYTES * 2;
    else      tail = ws;
    part     = (float*)tail;
    bpos     = (int*)(tail + PART_BYTES);
    flags    = (int*)(tail + PART_BYTES + BPOS_BYTES);
    chunkcnt = (int*)(tail + PART_BYTES + BPOS_BYTES + FLAG_BYTES);
    nbuf     = chunkcnt + 256;
    lenb     = nbuf + BB;

    len_kernel<<<1, 64, 0, stream>>>(mask, lenb);

    if (fast) {
        _Float16* Ah = (_Float16*)ws;
        _Float16* Al = (_Float16*)(ws + AH_BYTES);
        _Float16* Bh = (_Float16*)(ws + AH_BYTES * 2);
        _Float16* Bl = (_Float16*)(ws + AH_BYTES * 2 + BH_BYTES);
        conv_b_kernel<<<128, 256, 0, stream>>>(w1, Bh, Bl);
        conv_a_kernel<<<16384, 256, 0, stream>>>(hidden, Ah, Al);
        gemm_mfma_kernel<<<2048, 256, 0, stream>>>(Ah, Al, Bh, Bl, b1, w2, part);
    } else {
        mlp_gemm_kernel<<<dim3(NTILES_H, MM / BM), 256, 0, stream>>>(hidden, w1, b1, w2, part);
    }

    flags_kernel<<<256, 256, 0, stream>>>(part, u, b2, lenb, flags, chunkcnt);
    scan_kernel<<<256, 256, 0, stream>>>(flags, chunkcnt, bpos, nbuf, smask);
    pool_kernel<<<MM, 128, 0, stream>>>(hidden, bpos, nbuf, out);
    finalize_kernel<<<1, 64, 0, stream>>>(nbuf, lenb, out + P);
}

// Round 4
// 332.333 us; speedup vs baseline: 2.0778x; 1.1971x over previous
//
#include <hip/hip_runtime.h>
#include <hip/hip_bf16.h>
#include <stdint.h>

// Problem constants (from reference): B=16, L=4096, D=512, H=512
#define BB 16
#define LL 4096
#define DD 512
#define HH 512
#define MM (BB * LL)   // 65536 tokens
#define NTILES_H 8     // partial count (both paths)

typedef _Float16 f16x8 __attribute__((ext_vector_type(8)));
typedef float f32x4 __attribute__((ext_vector_type(4)));

// ===========================================================================
// conv_b + len (merged launch): w1 (D,H) -> Bh/Bl f16 tiles (scaled by 64,
// residual scaled 4096), n-major, fragment-packed + swizzled; block 128 does
// the per-row length binary search (mask rows are monotone 1..10..0).
// ===========================================================================
__global__ __launch_bounds__(256) void convb_len_kernel(
    const float* __restrict__ W1, _Float16* __restrict__ Bh, _Float16* __restrict__ Bl,
    const float* __restrict__ mask, int* __restrict__ lenb)
{
    if (blockIdx.x == 128) {
        const int b = threadIdx.x;
        if (b < BB) {
            const float* row = mask + b * LL;
            int lo = 0, hi = LL;
            while (lo < hi) {
                const int mid = (lo + hi) >> 1;
                if (row[mid] == 0.0f) hi = mid; else lo = mid + 1;
            }
            lenb[b] = lo;
        }
        return;
    }
    const int t    = blockIdx.x * 256 + threadIdx.x;   // 0 .. 32767
    const int tile = t >> 9;                           // ht*16 + kt
    const int u    = t & 511;
    const int nl   = u >> 2;
    const int q    = u & 3;
    const int ht   = tile >> 4;
    const int kt   = tile & 15;
    const int g    = q ^ (nl & 3) ^ ((nl >> 2) & 3);

    const int n = ht * 128 + nl;
    const int kbase = kt * 32;
    f16x8 h, l;
#pragma unroll
    for (int e = 0; e < 8; ++e) {
        const int k = kbase + ((e < 4) ? (4 * g + e) : (16 + 4 * g + (e - 4)));
        const float v = W1[(size_t)k * HH + n] * 64.0f;
        const _Float16 hh = (_Float16)v;
        const float r = v - (float)hh;
        h[e] = hh;
        l[e] = (_Float16)(r * 4096.0f);
    }
    *reinterpret_cast<f16x8*>(Bh + (size_t)tile * 4096 + u * 8) = h;
    *reinterpret_cast<f16x8*>(Bl + (size_t)tile * 4096 + u * 8) = l;
}

__device__ __forceinline__ void gload16(const void* g, void* l)
{
    __builtin_amdgcn_global_load_lds(
        (const __attribute__((address_space(1))) unsigned int*)g,
        (__attribute__((address_space(3))) unsigned int*)l, 16, 0, 0);
}

// ===========================================================================
// MFMA GEMM: stages fp32 hidden directly (no conv_a pass), splits to f16
// hi/lo in-register (bit-identical to the old conv_a arithmetic).
// LDS per buf: A fp32 [128 rows][8 chunks of 16B] = 16KB (chunk swizzled
// kc^(row&7) via per-lane global source, linear dest), Bh 8KB, Bl 8KB.
// ===========================================================================
__global__ __launch_bounds__(256, 2) void gemm_mfma_kernel(
    const float* __restrict__ A,
    const _Float16* __restrict__ Bh, const _Float16* __restrict__ Bl,
    const float* __restrict__ B1,    const float* __restrict__ W2,
    float* __restrict__ part)        // (8, M): p = ht*2 + wc
{
    __shared__ __align__(16) char lds[2][32768];   // [buf][A:0..16K | Bh:16K | Bl:24K]

    // XCD decode: d = x + 8*ht + 32*mt_local ; mt = x*64 + mt_local
    const int d  = blockIdx.x;
    const int x  = d & 7;
    const int ht = (d >> 3) & 3;
    const int mt = x * 64 + (d >> 5);

    const int tid  = threadIdx.x;
    const int lane = tid & 63;
    const int w    = tid >> 6;       // wave 0..3
    const int wr   = w >> 1;         // m half
    const int wc   = w & 1;          // n half
    const int c    = lane & 15;
    const int g    = lane >> 4;

    // A fragment slots: row r, chunks {g, g+4} swizzled by (r&7)==(c&7)
    int aoff0[4], aoff1[4], boff[4];
    const int qb = g ^ (c & 3) ^ ((c >> 2) & 3);
#pragma unroll
    for (int f = 0; f < 4; ++f) {
        const int r = wr * 64 + f * 16 + c;
        aoff0[f] = r * 128 + ((g ^ (c & 7)) << 4);
        aoff1[f] = r * 128 + (((g + 4) ^ (c & 7)) << 4);
        const int n_local = wc * 64 + f * 16 + c;
        boff[f] = n_local * 64 + (qb << 4);
    }

    f32x4 accM[4][4] = {};
    f32x4 accL[4][4] = {};

    auto stage = [&](int kt, int bsel) {
        char* l = &lds[bsel][0];
#pragma unroll
        for (int i = 0; i < 4; ++i) {                   // A: 1024 slots fp32
            const int s   = tid + i * 256;
            const int row = s >> 3;
            const int kc  = (s & 7) ^ (row & 7);
            gload16(A + ((size_t)(mt * 128 + row)) * DD + kt * 32 + kc * 4,
                    l + s * 16);
        }
        const _Float16* s2 = Bh + ((size_t)(ht * 16 + kt)) * 4096;
        const _Float16* s3 = Bl + ((size_t)(ht * 16 + kt)) * 4096;
#pragma unroll
        for (int i = 0; i < 2; ++i) {                   // B: 512 slots each
            const int s = tid + i * 256;
            gload16(s2 + s * 8, l + 16384 + s * 16);
            gload16(s3 + s * 8, l + 24576 + s * 16);
        }
    };

    stage(0, 0);
    int buf = 0;
    for (int kt = 0; kt < 16; ++kt) {
        __syncthreads();                 // staged buf ready; prev reads done
        if (kt + 1 < 16) stage(kt + 1, buf ^ 1);
        const char* base = &lds[buf][0];

        // A fragments: load fp32, split hi/lo (same rounding as old conv_a)
        f16x8 ah[4], al[4];
#pragma unroll
        for (int mf = 0; mf < 4; ++mf) {
            const f32x4 v0 = *reinterpret_cast<const f32x4*>(base + aoff0[mf]);
            const f32x4 v1 = *reinterpret_cast<const f32x4*>(base + aoff1[mf]);
            const float v[8] = {v0[0], v0[1], v0[2], v0[3], v1[0], v1[1], v1[2], v1[3]};
            f16x8 h, lo;
#pragma unroll
            for (int e = 0; e < 8; ++e) {
                const _Float16 hh = (_Float16)v[e];
                h[e]  = hh;
                lo[e] = (_Float16)((v[e] - (float)hh) * 4096.0f);
            }
            ah[mf] = h;
            al[mf] = lo;
        }
#pragma unroll
        for (int nf = 0; nf < 4; ++nf) {
            const f16x8 bh = *reinterpret_cast<const f16x8*>(base + 16384 + boff[nf]);
            const f16x8 bl = *reinterpret_cast<const f16x8*>(base + 24576 + boff[nf]);
#pragma unroll
            for (int mf = 0; mf < 4; ++mf) {
                accM[mf][nf] = __builtin_amdgcn_mfma_f32_16x16x32_f16(ah[mf], bh, accM[mf][nf], 0, 0, 0);
                accL[mf][nf] = __builtin_amdgcn_mfma_f32_16x16x32_f16(ah[mf], bl, accL[mf][nf], 0, 0, 0);
                accL[mf][nf] = __builtin_amdgcn_mfma_f32_16x16x32_f16(al[mf], bh, accL[mf][nf], 0, 0, 0);
            }
        }
        buf ^= 1;
    }

    // ---- epilogue: y = (accM + accL/4096)/64 + b1 ; relu ; dot w2 ---------
    float w2v[4], b1v[4];
#pragma unroll
    for (int nf = 0; nf < 4; ++nf) {
        const int n = ht * 128 + wc * 64 + nf * 16 + c;
        w2v[nf] = W2[n];
        b1v[nf] = B1[n];
    }
    float red[4][4];
#pragma unroll
    for (int mf = 0; mf < 4; ++mf)
#pragma unroll
        for (int r = 0; r < 4; ++r) {
            float s = 0.0f;
#pragma unroll
            for (int nf = 0; nf < 4; ++nf) {
                float y = (accM[mf][nf][r] + accL[mf][nf][r] * (1.0f / 4096.0f)) * (1.0f / 64.0f) + b1v[nf];
                y = (y > 0.0f) ? y : 0.0f;
                s = fmaf(y, w2v[nf], s);
            }
            red[mf][r] = s;
        }
#pragma unroll
    for (int step = 1; step < 16; step <<= 1)
#pragma unroll
        for (int mf = 0; mf < 4; ++mf)
#pragma unroll
            for (int r = 0; r < 4; ++r)
                red[mf][r] += __shfl_xor(red[mf][r], step);
    if (c == 0) {
        const int p = ht * 2 + wc;
#pragma unroll
        for (int mf = 0; mf < 4; ++mf)
#pragma unroll
            for (int r = 0; r < 4; ++r) {
                const int m = mt * 128 + wr * 64 + mf * 16 + g * 4 + r;
                part[(size_t)p * MM + m] = red[mf][r];
            }
    }
}

// ===========================================================================
// FALLBACK fp32 GEMM (used only if workspace too small)
// ===========================================================================
#define BM 64
#define BN 64
#define BK 32

__global__ __launch_bounds__(256) void mlp_gemm_kernel(
    const float* __restrict__ A, const float* __restrict__ W1,
    const float* __restrict__ B1, const float* __restrict__ W2,
    float* __restrict__ part)
{
    __shared__ __align__(16) float As[BK][BM];
    __shared__ __align__(16) float Bs[BK][BN];
    __shared__ float red[64][17];

    const int ht = blockIdx.x;
    const int mt = blockIdx.y;
    const int t  = threadIdx.x;
    const int tx = t & 15;
    const int ty = t >> 4;
    const int row0 = mt * BM;
    const int n0   = ht * BN;

    float acc[4][4];
#pragma unroll
    for (int i = 0; i < 4; ++i)
#pragma unroll
        for (int j = 0; j < 4; ++j) acc[i][j] = 0.0f;

    for (int k0 = 0; k0 < DD; k0 += BK) {
#pragma unroll
        for (int i = 0; i < 2; ++i) {
            const int idx = t + i * 256;
            const int m   = idx >> 3;
            const int kq  = idx & 7;
            const float4 a = *reinterpret_cast<const float4*>(
                &A[(size_t)(row0 + m) * DD + k0 + kq * 4]);
            As[kq * 4 + 0][m] = a.x;
            As[kq * 4 + 1][m] = a.y;
            As[kq * 4 + 2][m] = a.z;
            As[kq * 4 + 3][m] = a.w;
        }
#pragma unroll
        for (int i = 0; i < 2; ++i) {
            const int idx = t + i * 256;
            const int kk  = idx >> 4;
            const int nq  = idx & 15;
            const float4 bv = *reinterpret_cast<const float4*>(
                &W1[(size_t)(k0 + kk) * HH + n0 + nq * 4]);
            *reinterpret_cast<float4*>(&Bs[kk][nq * 4]) = bv;
        }
        __syncthreads();
#pragma unroll
        for (int k = 0; k < BK; ++k) {
            const float4 av = *reinterpret_cast<const float4*>(&As[k][ty * 4]);
            const float4 bv = *reinterpret_cast<const float4*>(&Bs[k][tx * 4]);
            const float a[4]  = {av.x, av.y, av.z, av.w};
            const float bb[4] = {bv.x, bv.y, bv.z, bv.w};
#pragma unroll
            for (int i = 0; i < 4; ++i)
#pragma unroll
                for (int j = 0; j < 4; ++j)
                    acc[i][j] = fmaf(a[i], bb[j], acc[i][j]);
        }
        __syncthreads();
    }

    const float4 b1v = *reinterpret_cast<const float4*>(&B1[n0 + tx * 4]);
    const float4 w2v = *reinterpret_cast<const float4*>(&W2[n0 + tx * 4]);
    const float b1a[4] = {b1v.x, b1v.y, b1v.z, b1v.w};
    const float w2a[4] = {w2v.x, w2v.y, w2v.z, w2v.w};
#pragma unroll
    for (int i = 0; i < 4; ++i) {
        float p = 0.0f;
#pragma unroll
        for (int j = 0; j < 4; ++j) {
            float y = acc[i][j] + b1a[j];
            y = (y > 0.0f) ? y : 0.0f;
            p = fmaf(y, w2a[j], p);
        }
        red[ty * 4 + i][tx] = p;
    }
    __syncthreads();
    if (t < 64) {
        float s = 0.0f;
#pragma unroll
        for (int q = 0; q < 16; ++q) s += red[t][q];
        part[(size_t)ht * MM + row0 + t] = s;
    }
}

// ===========================================================================
// Row scan: one block per batch row, 1024 threads x 4 tokens.
// flags + ballot/shfl prefix scan -> compacted bpos, nb, smask. One barrier.
// ===========================================================================
__global__ __launch_bounds__(1024) void rowscan_kernel(
    const float* __restrict__ part, const float* __restrict__ u,
    const float* __restrict__ b2,   const int* __restrict__ lenb,
    int* __restrict__ bpos, int* __restrict__ nb, float* __restrict__ smask_out)
{
    __shared__ int wtot[16];
    const int b    = blockIdx.x;
    const int tid  = threadIdx.x;
    const int lane = tid & 63;
    const int wid  = tid >> 6;
    const int base = b * LL;
    const int len  = lenb[b];
    const float b2v = b2[0];

    int h[4];
    int cnt = 0;
#pragma unroll
    for (int j = 0; j < 4; ++j) {
        const int l = tid * 4 + j;
        float logit = b2v;
#pragma unroll
        for (int p = 0; p < NTILES_H; ++p) logit += part[(size_t)p * MM + base + l];
        const float uu = u[base + l];
        const float xx = logit + logf(uu) - log1pf(-uu);
        int hh = (xx > 0.0f && l < len) ? 1 : 0;
        if (len < LL && l == len - 1) hh = 1;
        h[j] = hh;
        cnt += hh;
    }

    // wave-level inclusive scan of per-thread counts
    int incl = cnt;
#pragma unroll
    for (int s = 1; s < 64; s <<= 1) {
        const int v = __shfl_up(incl, s);
        if (lane >= s) incl += v;
    }
    if (lane == 63) wtot[wid] = incl;
    __syncthreads();

    int woff = 0, tot = 0;
#pragma unroll
    for (int i = 0; i < 16; ++i) {
        const int wi = wtot[i];
        woff += (i < wid) ? wi : 0;
        tot  += wi;
    }

    int pos = woff + incl - cnt;
#pragma unroll
    for (int j = 0; j < 4; ++j) {
        if (h[j]) {
            bpos[base + pos] = tid * 4 + j;
            ++pos;
        }
    }
#pragma unroll
    for (int j = 0; j < 4; ++j) {
        const int l = tid * 4 + j;
        smask_out[base + l] = (l < tot) ? 1.0f : 0.0f;
    }
    if (tid == 0) nb[b] = tot;
}

// ===========================================================================
// Segment mean pooling
// ===========================================================================
__global__ __launch_bounds__(128) void pool_kernel(
    const float* __restrict__ hidden, const int* __restrict__ bpos,
    const int* __restrict__ nb, float* __restrict__ out)
{
    const int blk = blockIdx.x;
    const int b   = blk >> 12;
    const int s   = blk & (LL - 1);
    const int tid = threadIdx.x;
    const int base = b * LL;

    float ax = 0.0f, ay = 0.0f, az = 0.0f, aw = 0.0f;
    const int n = nb[b];
    if (s < n) {
        const int start = (s == 0) ? 0 : (bpos[base + s - 1] + 1);
        const int end   = bpos[base + s];
        const float inv = 1.0f / (float)(end - start + 1);
        for (int tkn = start; tkn <= end; ++tkn) {
            const float4 v = *reinterpret_cast<const float4*>(
                &hidden[((size_t)(base + tkn)) * DD + tid * 4]);
            ax += v.x; ay += v.y; az += v.z; aw += v.w;
        }
        ax *= inv; ay *= inv; az *= inv; aw *= inv;
    }
    float4 r; r.x = ax; r.y = ay; r.z = az; r.w = aw;
    *reinterpret_cast<float4*>(&out[((size_t)(base + s)) * DD + tid * 4]) = r;
}

// ===========================================================================
// Scalars
// ===========================================================================
__global__ void finalize_kernel(
    const int* __restrict__ nb, const int* __restrict__ lenb,
    float* __restrict__ out)
{
    if (threadIdx.x == 0 && blockIdx.x == 0) {
        int k = 0, n = 0;
        for (int b = 0; b < BB; ++b) { k += nb[b]; n += lenb[b]; }
        const double dk = (double)k, dn = (double)n, p = 0.25;
        const double logc = lgamma(dn + 1.0) - lgamma(dk + 1.0) - lgamma(dn - dk + 1.0);
        const double loss = -(logc + dk * log(p) + (dn - dk) * log1p(-p)) / dn;
        out[0] = (float)loss;
        out[1] = (float)k;
        out[2] = (float)n;
    }
}

// ===========================================================================
extern "C" void kernel_launch(void* const* d_in, const int* in_sizes, int n_in,
                              void* d_out, int out_size, void* d_ws, size_t ws_size,
                              hipStream_t stream) {
    const float* hidden = (const float*)d_in[0];
    const float* mask   = (const float*)d_in[1];
    const float* u      = (const float*)d_in[2];
    const float* w1     = (const float*)d_in[3];
    const float* b1     = (const float*)d_in[4];
    const float* w2     = (const float*)d_in[5];
    const float* b2     = (const float*)d_in[6];
    float* out = (float*)d_out;

    const size_t BH_BYTES   = (size_t)64 * 4096 * 2;     // 512 KB each
    const size_t PART_BYTES = (size_t)NTILES_H * MM * 4; // 2 MB
    const size_t BPOS_BYTES = (size_t)MM * 4;            // 256 KB
    const size_t need = BH_BYTES * 2 + PART_BYTES + BPOS_BYTES + 4096;

    const size_t P = (size_t)MM * DD;
    float* smask = out + P + 3;

    char* ws = (char*)d_ws;
    const bool fast = (ws_size >= need);

    char* tail = fast ? (ws + BH_BYTES * 2) : ws;
    float* part = (float*)tail;
    int*   bpos = (int*)(tail + PART_BYTES);
    int*   nbuf = (int*)(tail + PART_BYTES + BPOS_BYTES);
    int*   lenb = nbuf + BB;

    if (fast) {
        _Float16* Bh = (_Float16*)ws;
        _Float16* Bl = (_Float16*)(ws + BH_BYTES);
        convb_len_kernel<<<129, 256, 0, stream>>>(w1, Bh, Bl, mask, lenb);
        gemm_mfma_kernel<<<2048, 256, 0, stream>>>(hidden, Bh, Bl, b1, w2, part);
    } else {
        convb_len_kernel<<<129, 256, 0, stream>>>(w1, (_Float16*)ws, (_Float16*)ws, mask, lenb); // lenb still needed
        mlp_gemm_kernel<<<dim3(NTILES_H, MM / BM), 256, 0, stream>>>(hidden, w1, b1, w2, part);
    }

    rowscan_kernel<<<BB, 1024, 0, stream>>>(part, u, b2, lenb, bpos, nbuf, smask);
    pool_kernel<<<MM, 128, 0, stream>>>(hidden, bpos, nbuf, out);
    finalize_kernel<<<1, 64, 0, stream>>>(nbuf, lenb, out + P);
}